// Round 12
// baseline (16.776 us; speedup 1.0000x reference)
//
#include <hip/hip_runtime.h>

#define DIM 10
#define BATCH 65536

typedef _Float16 h2 __attribute__((ext_vector_type(2)));

#if defined(__has_builtin)
#  if __has_builtin(__builtin_amdgcn_fdot2)
#    define HAS_FDOT2 1
#  endif
#endif
#ifndef HAS_FDOT2
#  define HAS_FDOT2 0
#endif

// Code-size round, take 2 (register accumulators this time).
// Conv restructured as a ROLLED loop over source rows p (10 iters, p is
// wave-uniform) with q-slots unrolled inside -> every accumulator index is
// STATIC.  3-row register window: source row p scatters only into rows
// p-1 (Wp), p (Wc), p+1 (Wn).  Row p-1 retires each iteration (relu -> vc
// registers + one ds_write of its row-sum).  Wp starts at -1e30 so the p=0
// junk retire contributes exactly 0 (branchless).  LDS planes live OUTSIDE
// the staging region -> no aliasing anywhere.  Code ~27KB -> ~12KB to test
// the I$-cold-fetch theory of the invariant ~5us base.
__launch_bounds__(64, 1)
__global__ void net_kernel(const float* __restrict__ x,
                           const float* __restrict__ w1,
                           const float* __restrict__ b1,
                           const float* __restrict__ w2,
                           const float* __restrict__ b2,
                           const float* __restrict__ fc1_w,
                           const float* __restrict__ fc1_b,
                           const float* __restrict__ fc2_w,
                           const float* __restrict__ fc2_b,
                           float* __restrict__ out) {
    // LDS words: [0,6400) x staging; [6400,6720) rowh u16[10][64];
    // [6720,7360) vr f32[10][64].  Total 29,440 B.
    __shared__ __align__(16) float smem[7360];

    const int lane = threadIdx.x;                 // 64-thread block = 1 wave
    const size_t blk0 = (size_t)blockIdx.x * 64;

    // ---- Phase 1: wave-private coalesced staging (25 x 1 KiB) ----
    const float* gbase = x + blk0 * (DIM * DIM);
    #pragma unroll
    for (int c = 0; c < 25; ++c) {
        __builtin_amdgcn_global_load_lds(
            (const __attribute__((address_space(1))) void*)(gbase + c * 256 + lane * 4),
            (__attribute__((address_space(3))) void*)(smem + c * 256),
            16, 0, 0);
    }

    // ---- weights -> packed f16 (uniform loads; hides staging latency) ----
    h2 W1h[5], B1h[5], W2h[5][9];
    #pragma unroll
    for (int cp = 0; cp < 5; ++cp) {
        W1h[cp][0] = (_Float16)w1[2 * cp];     W1h[cp][1] = (_Float16)w1[2 * cp + 1];
        B1h[cp][0] = (_Float16)b1[2 * cp];     B1h[cp][1] = (_Float16)b1[2 * cp + 1];
        #pragma unroll
        for (int k = 0; k < 9; ++k) {
            W2h[cp][k][0] = (_Float16)w2[(2 * cp) * 9 + k];
            W2h[cp][k][1] = (_Float16)w2[(2 * cp + 1) * 9 + k];
        }
    }
    const float B2 = b2[0];

    asm volatile("s_waitcnt vmcnt(0)" ::: "memory");

    // ---- Phase 2: per-thread row/col sums from own staged element ----
    float row[DIM], col[DIM];
    #pragma unroll
    for (int i = 0; i < DIM; ++i) { row[i] = 0.f; col[i] = 0.f; }
    const float4* xb = reinterpret_cast<const float4*>(smem + lane * (DIM * DIM));
    #pragma unroll
    for (int t = 0; t < 25; ++t) {
        const float4 v = xb[t];
        const int e0 = t * 4;
        row[(e0 + 0) / DIM] += v.x; col[(e0 + 0) % DIM] += v.x;
        row[(e0 + 1) / DIM] += v.y; col[(e0 + 1) % DIM] += v.y;
        row[(e0 + 2) / DIM] += v.z; col[(e0 + 2) % DIM] += v.z;
        row[(e0 + 3) / DIM] += v.w; col[(e0 + 3) % DIM] += v.w;
    }

    // ---- Phase 2.5: rowh SoA plane (dynamic-p reads later); col as f16 regs ----
    _Float16* rowh = reinterpret_cast<_Float16*>(smem + 6400);  // [10][64]
    #pragma unroll
    for (int r = 0; r < DIM; ++r) rowh[r * 64 + lane] = (_Float16)row[r];
    _Float16 ch[DIM];
    #pragma unroll
    for (int q = 0; q < DIM; ++q) ch[q] = (_Float16)col[q];
    float* vrp = smem + 6720;                                   // [10][64] f32

    // ---- Phase 3: rolled-p conv with 3-row register window ----
    float Wp[DIM], Wc[DIM], Wn[DIM], vc[DIM];
    #pragma unroll
    for (int j = 0; j < DIM; ++j) {
        Wp[j] = -1e30f;    // row -1: junk; relu() at retire -> exact 0
        Wc[j] = B2;        // row 0
        Wn[j] = B2;        // row 1
        vc[j] = 0.f;
    }

    #pragma unroll 1
    for (int p = 0; p < DIM; ++p) {
        const _Float16 rph = rowh[p * 64 + lane];   // uniform p, lane column
        #pragma unroll
        for (int q = 0; q < DIM; ++q) {
            if (p >= q) {                           // uniform scalar branch
                const _Float16 eh = rph + ch[q];
                h2 e2; e2[0] = eh; e2[1] = eh;
#if HAS_FDOT2
                h2 g[5];
                #pragma unroll
                for (int cp = 0; cp < 5; ++cp)
                    g[cp] = __builtin_elementwise_max(
                        __builtin_elementwise_fma(W1h[cp], e2, B1h[cp]),
                        (h2){(_Float16)0, (_Float16)0});
                // taps: a=0 -> Wn (k=b), a=1 -> Wc (k=3+b), a=2 -> Wp (k=6+b);
                // col j = q+1-b (static), skip out-of-range j.
                #pragma unroll
                for (int b = 0; b < 3; ++b) {
                    const int j = q + 1 - b;
                    if (j < 0 || j >= DIM) continue;     // folds at compile time
                    float t0 = Wn[j], t1 = Wc[j], t2 = Wp[j];
                    #pragma unroll
                    for (int cp = 0; cp < 5; ++cp) {
                        t0 = __builtin_amdgcn_fdot2(g[cp], W2h[cp][b],     t0, false);
                        t1 = __builtin_amdgcn_fdot2(g[cp], W2h[cp][3 + b], t1, false);
                        t2 = __builtin_amdgcn_fdot2(g[cp], W2h[cp][6 + b], t2, false);
                    }
                    Wn[j] = t0; Wc[j] = t1; Wp[j] = t2;
                }
#else
                float gs[10];
                #pragma unroll
                for (int cp = 0; cp < 5; ++cp) {
                    const float ev = (float)eh;
                    gs[2*cp]   = fmaxf(fmaf((float)W1h[cp][0], ev, (float)B1h[cp][0]), 0.f);
                    gs[2*cp+1] = fmaxf(fmaf((float)W1h[cp][1], ev, (float)B1h[cp][1]), 0.f);
                }
                #pragma unroll
                for (int b = 0; b < 3; ++b) {
                    const int j = q + 1 - b;
                    if (j < 0 || j >= DIM) continue;
                    float t0 = Wn[j], t1 = Wc[j], t2 = Wp[j];
                    #pragma unroll
                    for (int c2 = 0; c2 < 10; ++c2) {
                        t0 = fmaf(gs[c2], (float)W2h[c2 >> 1][b]    [c2 & 1], t0);
                        t1 = fmaf(gs[c2], (float)W2h[c2 >> 1][3 + b][c2 & 1], t1);
                        t2 = fmaf(gs[c2], (float)W2h[c2 >> 1][6 + b][c2 & 1], t2);
                    }
                    Wn[j] = t0; Wc[j] = t1; Wp[j] = t2;
                }
#endif
            }
        }
        // retire row p-1 (in Wp).  p=0: Wp = -1e30 + eps -> relu = 0 exactly.
        float s = 0.f;
        #pragma unroll
        for (int j = 0; j < DIM; ++j) {
            const float m = fmaxf(Wp[j], 0.f);
            vc[j] += m;
            s += m;
        }
        const int rs = (p > 0) ? (p - 1) : 0;   // p=0 junk write, overwritten at p=1
        vrp[rs * 64 + lane] = s;
        // rotate window
        #pragma unroll
        for (int j = 0; j < DIM; ++j) { Wp[j] = Wc[j]; Wc[j] = Wn[j]; Wn[j] = B2; }
    }
    // final retire: row 9 sits in Wp after the last rotation
    float vr9 = 0.f;
    #pragma unroll
    for (int j = 0; j < DIM; ++j) {
        const float m = fmaxf(Wp[j], 0.f);
        vc[j] += m;
        vr9 += m;
    }

    // ---- Epilogue: vsum = vr + vc; FC head ----
    float vsum[DIM];
    #pragma unroll
    for (int k = 0; k < 9; ++k) vsum[k] = vrp[k * 64 + lane] + vc[k];
    vsum[9] = vr9 + vc[9];

    float hid[4];
    #pragma unroll
    for (int t = 0; t < 4; ++t) {
        float a = fc1_b[t];
        #pragma unroll
        for (int k = 0; k < DIM; ++k) a = fmaf(vsum[k], fc1_w[t * DIM + k], a);
        hid[t] = fmaxf(a, 0.f);
    }
    float o0 = fc2_b[0], o1 = fc2_b[1];
    #pragma unroll
    for (int t = 0; t < 4; ++t) {
        o0 = fmaf(hid[t], fc2_w[t], o0);
        o1 = fmaf(hid[t], fc2_w[4 + t], o1);
    }
    reinterpret_cast<float2*>(out)[blk0 + lane] = make_float2(o0, o1);
}

extern "C" void kernel_launch(void* const* d_in, const int* in_sizes, int n_in,
                              void* d_out, int out_size, void* d_ws, size_t ws_size,
                              hipStream_t stream) {
    const float* x     = (const float*)d_in[0];
    const float* w1    = (const float*)d_in[1];
    const float* b1    = (const float*)d_in[2];
    const float* w2    = (const float*)d_in[3];
    const float* b2    = (const float*)d_in[4];
    const float* fc1_w = (const float*)d_in[5];
    const float* fc1_b = (const float*)d_in[6];
    const float* fc2_w = (const float*)d_in[7];
    const float* fc2_b = (const float*)d_in[8];
    float* out = (float*)d_out;

    const int block = 64;                 // 1 wave per block
    const int grid = BATCH / block;       // 1024 blocks, 4 per CU
    net_kernel<<<grid, block, 0, stream>>>(x, w1, b1, w2, b2, fc1_w, fc1_b,
                                           fc2_w, fc2_b, out);
}

// Round 13
// 15.116 us; speedup vs baseline: 1.1098x; 1.1098x over previous
//
#include <hip/hip_runtime.h>

#define DIM 10
#define BATCH 65536

typedef _Float16 h2 __attribute__((ext_vector_type(2)));

#if defined(__has_builtin)
#  if __has_builtin(__builtin_amdgcn_fdot2)
#    define HAS_FDOT2 1
#  endif
#endif
#ifndef HAS_FDOT2
#  define HAS_FDOT2 0
#endif

// Pixel-split occupancy round: 2 waves per 64-element tile (128-thr block,
// 2048 waves = 2/SIMD).  Wave 0 computes even-index pixels, wave 1 odd-index
// (WAVE-UNIFORM split -> each wave issues only ~half the conv, unlike the
// R3 channel split where both lanes still walked all 55 pixels).  Partial
// acc merged through the staging LDS region (dead after phase2).  Mechanism:
// at 1 wave/SIMD the ~3-4us staging drain + dep stalls are fully exposed
// (R10 VALUBusy ~30%); a second resident wave covers them.
template <int PAR>
__device__ __forceinline__ void conv_half(const _Float16* rh, const _Float16* ch,
                                          const h2* W1h, const h2* B1h,
                                          const h2 (*W2h)[9],
                                          float acc[DIM][DIM]) {
    #pragma unroll
    for (int p = 0; p < DIM; ++p) {
        #pragma unroll
        for (int q = 0; q <= p; ++q) {
            const int t = p * (p + 1) / 2 + q;    // pixel index, compile-time
            if ((t & 1) != PAR) continue;
            const _Float16 eh = rh[p] + ch[q];
            h2 e2; e2[0] = eh; e2[1] = eh;
#if HAS_FDOT2
            h2 g[5];
            #pragma unroll
            for (int cp = 0; cp < 5; ++cp)
                g[cp] = __builtin_elementwise_max(
                    __builtin_elementwise_fma(W1h[cp], e2, B1h[cp]),
                    (h2){(_Float16)0, (_Float16)0});
            #pragma unroll
            for (int a = 0; a < 3; ++a) {
                const int i = p + 1 - a;
                if (i < 0 || i >= DIM) continue;          // folds at compile time
                #pragma unroll
                for (int bb = 0; bb < 3; ++bb) {
                    const int j = q + 1 - bb;
                    if (j < 0 || j >= DIM) continue;
                    const int k = a * 3 + bb;
                    float t0 = acc[i][j];
                    #pragma unroll
                    for (int cp = 0; cp < 5; ++cp)
                        t0 = __builtin_amdgcn_fdot2(g[cp], W2h[cp][k], t0, false);
                    acc[i][j] = t0;
                }
            }
#else
            float gs[10];
            const float ev = (float)eh;
            #pragma unroll
            for (int cp = 0; cp < 5; ++cp) {
                gs[2*cp]   = fmaxf(fmaf((float)W1h[cp][0], ev, (float)B1h[cp][0]), 0.f);
                gs[2*cp+1] = fmaxf(fmaf((float)W1h[cp][1], ev, (float)B1h[cp][1]), 0.f);
            }
            #pragma unroll
            for (int a = 0; a < 3; ++a) {
                const int i = p + 1 - a;
                if (i < 0 || i >= DIM) continue;
                #pragma unroll
                for (int bb = 0; bb < 3; ++bb) {
                    const int j = q + 1 - bb;
                    if (j < 0 || j >= DIM) continue;
                    const int k = a * 3 + bb;
                    float t0 = acc[i][j];
                    #pragma unroll
                    for (int cp = 0; cp < 5; ++cp) {
                        t0 = fmaf(gs[2*cp],   (float)W2h[cp][k][0], t0);
                        t0 = fmaf(gs[2*cp+1], (float)W2h[cp][k][1], t0);
                    }
                    acc[i][j] = t0;
                }
            }
#endif
        }
    }
}

__launch_bounds__(128, 2)
__global__ void net_kernel(const float* __restrict__ x,
                           const float* __restrict__ w1,
                           const float* __restrict__ b1,
                           const float* __restrict__ w2,
                           const float* __restrict__ b2,
                           const float* __restrict__ fc1_w,
                           const float* __restrict__ fc1_b,
                           const float* __restrict__ fc2_w,
                           const float* __restrict__ fc2_b,
                           float* __restrict__ out) {
    __shared__ __align__(16) float smem[6400];   // 64 elems x 100 f (25.6 KB)

    const int tid  = threadIdx.x;
    const int lane = tid & 63;
    const int w    = __builtin_amdgcn_readfirstlane(tid >> 6);  // 0 or 1, uniform
    const size_t blk0 = (size_t)blockIdx.x * 64;

    // ---- Phase 1: cooperative staging (wave0: chunks 0-12, wave1: 13-24) ----
    const float* gbase = x + blk0 * (DIM * DIM);
    if (w == 0) {
        #pragma unroll
        for (int c = 0; c < 13; ++c)
            __builtin_amdgcn_global_load_lds(
                (const __attribute__((address_space(1))) void*)(gbase + c * 256 + lane * 4),
                (__attribute__((address_space(3))) void*)(smem + c * 256),
                16, 0, 0);
    } else {
        #pragma unroll
        for (int c = 13; c < 25; ++c)
            __builtin_amdgcn_global_load_lds(
                (const __attribute__((address_space(1))) void*)(gbase + c * 256 + lane * 4),
                (__attribute__((address_space(3))) void*)(smem + c * 256),
                16, 0, 0);
    }

    // ---- weights -> packed f16 (both waves; hides staging latency) ----
    h2 W1h[5], B1h[5], W2h[5][9];
    #pragma unroll
    for (int cp = 0; cp < 5; ++cp) {
        W1h[cp][0] = (_Float16)w1[2 * cp];     W1h[cp][1] = (_Float16)w1[2 * cp + 1];
        B1h[cp][0] = (_Float16)b1[2 * cp];     B1h[cp][1] = (_Float16)b1[2 * cp + 1];
        #pragma unroll
        for (int k = 0; k < 9; ++k) {
            W2h[cp][k][0] = (_Float16)w2[(2 * cp) * 9 + k];
            W2h[cp][k][1] = (_Float16)w2[(2 * cp + 1) * 9 + k];
        }
    }
    const float B2 = b2[0];

    __syncthreads();   // staging complete (implies vmcnt(0))

    // ---- Phase 2: rowcol for element `lane` (both waves, duplicated) ----
    float row[DIM], col[DIM];
    #pragma unroll
    for (int i = 0; i < DIM; ++i) { row[i] = 0.f; col[i] = 0.f; }
    const float4* xb = reinterpret_cast<const float4*>(smem + lane * (DIM * DIM));
    #pragma unroll
    for (int t = 0; t < 25; ++t) {
        const float4 v = xb[t];
        const int e0 = t * 4;
        row[(e0 + 0) / DIM] += v.x; col[(e0 + 0) % DIM] += v.x;
        row[(e0 + 1) / DIM] += v.y; col[(e0 + 1) % DIM] += v.y;
        row[(e0 + 2) / DIM] += v.z; col[(e0 + 2) % DIM] += v.z;
        row[(e0 + 3) / DIM] += v.w; col[(e0 + 3) % DIM] += v.w;
    }

    __syncthreads();   // all phase-2 reads done before smem is reused for merge

    _Float16 rh[DIM], ch[DIM];
    #pragma unroll
    for (int i = 0; i < DIM; ++i) { rh[i] = (_Float16)row[i]; ch[i] = (_Float16)col[i]; }

    // ---- Phase 3: half-conv per wave (b2 folded into wave0's init only) ----
    float acc[DIM][DIM];
    const float ainit = (w == 0) ? B2 : 0.0f;
    #pragma unroll
    for (int i = 0; i < DIM; ++i)
        #pragma unroll
        for (int j = 0; j < DIM; ++j) acc[i][j] = ainit;

    if (w == 0) conv_half<0>(rh, ch, W1h, B1h, W2h, acc);
    else        conv_half<1>(rh, ch, W1h, B1h, W2h, acc);

    // ---- merge: wave1 -> LDS (staging region, now dead), wave0 adds ----
    if (w == 1) {
        float4* mb = reinterpret_cast<float4*>(smem + lane * (DIM * DIM));
        #pragma unroll
        for (int t = 0; t < 25; ++t) {
            const int f = 4 * t;
            mb[t] = make_float4(acc[f / 10][f % 10],       acc[(f+1) / 10][(f+1) % 10],
                                acc[(f+2) / 10][(f+2) % 10], acc[(f+3) / 10][(f+3) % 10]);
        }
    }
    __syncthreads();
    if (w == 0) {
        const float4* mb = reinterpret_cast<const float4*>(smem + lane * (DIM * DIM));
        #pragma unroll
        for (int t = 0; t < 25; ++t) {
            const float4 v = mb[t];
            const int f = 4 * t;
            acc[f / 10][f % 10]         += v.x;
            acc[(f+1) / 10][(f+1) % 10] += v.y;
            acc[(f+2) / 10][(f+2) % 10] += v.z;
            acc[(f+3) / 10][(f+3) % 10] += v.w;
        }

        // ---- Epilogue (wave 0 only): relu, vsum, FC head, store ----
        float vsum[DIM];
        #pragma unroll
        for (int k = 0; k < DIM; ++k) vsum[k] = 0.f;
        #pragma unroll
        for (int i = 0; i < DIM; ++i) {
            #pragma unroll
            for (int j = 0; j < DIM; ++j) {
                const float m = fmaxf(acc[i][j], 0.f);
                vsum[i] += m;
                vsum[j] += m;
            }
        }
        float hid[4];
        #pragma unroll
        for (int t = 0; t < 4; ++t) {
            float a = fc1_b[t];
            #pragma unroll
            for (int k = 0; k < DIM; ++k) a = fmaf(vsum[k], fc1_w[t * DIM + k], a);
            hid[t] = fmaxf(a, 0.f);
        }
        float o0 = fc2_b[0], o1 = fc2_b[1];
        #pragma unroll
        for (int t = 0; t < 4; ++t) {
            o0 = fmaf(hid[t], fc2_w[t], o0);
            o1 = fmaf(hid[t], fc2_w[4 + t], o1);
        }
        reinterpret_cast<float2*>(out)[blk0 + lane] = make_float2(o0, o1);
    }
}

extern "C" void kernel_launch(void* const* d_in, const int* in_sizes, int n_in,
                              void* d_out, int out_size, void* d_ws, size_t ws_size,
                              hipStream_t stream) {
    const float* x     = (const float*)d_in[0];
    const float* w1    = (const float*)d_in[1];
    const float* b1    = (const float*)d_in[2];
    const float* w2    = (const float*)d_in[3];
    const float* b2    = (const float*)d_in[4];
    const float* fc1_w = (const float*)d_in[5];
    const float* fc1_b = (const float*)d_in[6];
    const float* fc2_w = (const float*)d_in[7];
    const float* fc2_b = (const float*)d_in[8];
    float* out = (float*)d_out;

    const int block = 128;                // 2 waves, one 64-element tile
    const int grid = BATCH / 64;          // 1024 blocks, 4/CU -> 2 waves/SIMD
    net_kernel<<<grid, block, 0, stream>>>(x, w1, b1, w2, b2, fc1_w, fc1_b,
                                           fc2_w, fc2_b, out);
}

// Round 14
// 14.301 us; speedup vs baseline: 1.1730x; 1.0570x over previous
//
#include <hip/hip_runtime.h>

#define DIM 10
#define BATCH 65536

typedef _Float16 h2 __attribute__((ext_vector_type(2)));

#if defined(__has_builtin)
#  if __has_builtin(__builtin_amdgcn_fdot2)
#    define HAS_FDOT2 1
#  endif
#endif
#ifndef HAS_FDOT2
#  define HAS_FDOT2 0
#endif

// FINAL (R10 restoration): best measured configuration, 14.16 us.
// - 1024 blocks x 64 threads (1 wave/block, 4 blocks/CU)
// - wave-private global_load_lds staging (25 x 1 KiB), no barrier, single
//   wave-level vmcnt(0)
// - f16 weight setup under staging latency
// - conv: 55 lower-triangle pixels, direct-accumulate 5-deep fdot2 chains
//   into acc[i][j] (invalid taps compile away), b2 folded into acc init
// Measured floor decomposition @ ~1.45 GHz sustained: cold kernarg/weight
// loads ~1us + staging ~3us + VALU issue ~5.5-6us + dispatch/ramp/tail ~2-3us
// = 13-14.5us.  Six structural alternatives (lane-split, kernel-split, PWL
// table, rolled conv x2, pixel-split 2-wave) all returned >= their added
// issue cost: the residual stall is global (ramp/clock/serial-chain), not
// hideable at this problem size.
__launch_bounds__(64, 1)
__global__ void net_kernel(const float* __restrict__ x,
                           const float* __restrict__ w1,
                           const float* __restrict__ b1,
                           const float* __restrict__ w2,
                           const float* __restrict__ b2,
                           const float* __restrict__ fc1_w,
                           const float* __restrict__ fc1_b,
                           const float* __restrict__ fc2_w,
                           const float* __restrict__ fc2_b,
                           float* __restrict__ out) {
    __shared__ __align__(16) float xs[64 * DIM * DIM];   // 25.6 KiB

    const int lane = threadIdx.x;                 // 64-thread block = 1 wave
    const size_t blk0 = (size_t)blockIdx.x * 64;

    // ---- Phase 1: wave-private coalesced staging (25 x 1 KiB) ----
    const float* gbase = x + blk0 * (DIM * DIM);
    #pragma unroll
    for (int c = 0; c < 25; ++c) {
        __builtin_amdgcn_global_load_lds(
            (const __attribute__((address_space(1))) void*)(gbase + c * 256 + lane * 4),
            (__attribute__((address_space(3))) void*)(xs + c * 256),
            16, 0, 0);
    }

    // ---- weights -> packed f16 (uniform loads; hides staging latency) ----
    h2 W1h[5], B1h[5], W2h[5][9];
    #pragma unroll
    for (int cp = 0; cp < 5; ++cp) {
        W1h[cp][0] = (_Float16)w1[2 * cp];     W1h[cp][1] = (_Float16)w1[2 * cp + 1];
        B1h[cp][0] = (_Float16)b1[2 * cp];     B1h[cp][1] = (_Float16)b1[2 * cp + 1];
        #pragma unroll
        for (int k = 0; k < 9; ++k) {
            W2h[cp][k][0] = (_Float16)w2[(2 * cp) * 9 + k];
            W2h[cp][k][1] = (_Float16)w2[(2 * cp + 1) * 9 + k];
        }
    }
    const float B2 = b2[0];

    // wave-level wait for our own 25 chunks (no block barrier needed)
    asm volatile("s_waitcnt vmcnt(0)" ::: "memory");

    // ---- Phase 2: per-thread row/col sums from own LDS row ----
    float row[DIM], col[DIM];
    #pragma unroll
    for (int i = 0; i < DIM; ++i) { row[i] = 0.f; col[i] = 0.f; }
    const float4* xb = reinterpret_cast<const float4*>(xs + lane * (DIM * DIM));
    #pragma unroll
    for (int t = 0; t < 25; ++t) {
        const float4 v = xb[t];
        const int e0 = t * 4;
        row[(e0 + 0) / DIM] += v.x; col[(e0 + 0) % DIM] += v.x;
        row[(e0 + 1) / DIM] += v.y; col[(e0 + 1) % DIM] += v.y;
        row[(e0 + 2) / DIM] += v.z; col[(e0 + 2) % DIM] += v.z;
        row[(e0 + 3) / DIM] += v.w; col[(e0 + 3) % DIM] += v.w;
    }

    // ---- Phase 3: conv, direct-accumulate (b2 folded into init) ----
    float acc[DIM][DIM];
    #pragma unroll
    for (int i = 0; i < DIM; ++i)
        #pragma unroll
        for (int j = 0; j < DIM; ++j) acc[i][j] = B2;

    const h2 zero_h2 = (h2){(_Float16)0, (_Float16)0};

    #pragma unroll
    for (int p = 0; p < DIM; ++p) {
        #pragma unroll
        for (int q = 0; q <= p; ++q) {
            const float ev = row[p] + col[q];
#if HAS_FDOT2
            const _Float16 eh = (_Float16)ev;
            const h2 e2 = (h2){eh, eh};
            h2 g[5];
            #pragma unroll
            for (int cp = 0; cp < 5; ++cp) {
                g[cp] = __builtin_elementwise_max(
                    __builtin_elementwise_fma(W1h[cp], e2, B1h[cp]), zero_h2);
            }
            // per VALID tap: 5-deep fdot2 chain straight into acc[i][j]
            #pragma unroll
            for (int a = 0; a < 3; ++a) {
                const int i = p + 1 - a;
                if (i < 0 || i >= DIM) continue;          // folds at compile time
                #pragma unroll
                for (int bb = 0; bb < 3; ++bb) {
                    const int j = q + 1 - bb;
                    if (j < 0 || j >= DIM) continue;
                    const int k = a * 3 + bb;
                    float t0 = acc[i][j];
                    #pragma unroll
                    for (int cp = 0; cp < 5; ++cp)
                        t0 = __builtin_amdgcn_fdot2(g[cp], W2h[cp][k], t0, false);
                    acc[i][j] = t0;
                }
            }
#else
            float gs[10];
            #pragma unroll
            for (int cp = 0; cp < 5; ++cp) {
                gs[2*cp]   = fmaxf(fmaf((float)W1h[cp][0], ev, (float)B1h[cp][0]), 0.f);
                gs[2*cp+1] = fmaxf(fmaf((float)W1h[cp][1], ev, (float)B1h[cp][1]), 0.f);
            }
            #pragma unroll
            for (int a = 0; a < 3; ++a) {
                const int i = p + 1 - a;
                if (i < 0 || i >= DIM) continue;
                #pragma unroll
                for (int bb = 0; bb < 3; ++bb) {
                    const int j = q + 1 - bb;
                    if (j < 0 || j >= DIM) continue;
                    const int k = a * 3 + bb;
                    float t0 = acc[i][j];
                    #pragma unroll
                    for (int cp = 0; cp < 5; ++cp) {
                        t0 = fmaf(gs[2*cp],   (float)W2h[cp][k][0], t0);
                        t0 = fmaf(gs[2*cp+1], (float)W2h[cp][k][1], t0);
                    }
                    acc[i][j] = t0;
                }
            }
#endif
        }
    }

    // ---- m = relu(acc) (b2 already folded); v[k] = row-sum + col-sum ----
    float vsum[DIM];
    #pragma unroll
    for (int k = 0; k < DIM; ++k) vsum[k] = 0.f;
    #pragma unroll
    for (int i = 0; i < DIM; ++i) {
        #pragma unroll
        for (int j = 0; j < DIM; ++j) {
            const float m = fmaxf(acc[i][j], 0.f);
            vsum[i] += m;
            vsum[j] += m;
        }
    }

    // ---- FC head ----
    float hid[4];
    #pragma unroll
    for (int t = 0; t < 4; ++t) {
        float a = fc1_b[t];
        #pragma unroll
        for (int k = 0; k < DIM; ++k) a = fmaf(vsum[k], fc1_w[t * DIM + k], a);
        hid[t] = fmaxf(a, 0.f);
    }
    float o0 = fc2_b[0], o1 = fc2_b[1];
    #pragma unroll
    for (int t = 0; t < 4; ++t) {
        o0 = fmaf(hid[t], fc2_w[t], o0);
        o1 = fmaf(hid[t], fc2_w[4 + t], o1);
    }
    reinterpret_cast<float2*>(out)[blk0 + lane] = make_float2(o0, o1);
}

extern "C" void kernel_launch(void* const* d_in, const int* in_sizes, int n_in,
                              void* d_out, int out_size, void* d_ws, size_t ws_size,
                              hipStream_t stream) {
    const float* x     = (const float*)d_in[0];
    const float* w1    = (const float*)d_in[1];
    const float* b1    = (const float*)d_in[2];
    const float* w2    = (const float*)d_in[3];
    const float* b2    = (const float*)d_in[4];
    const float* fc1_w = (const float*)d_in[5];
    const float* fc1_b = (const float*)d_in[6];
    const float* fc2_w = (const float*)d_in[7];
    const float* fc2_b = (const float*)d_in[8];
    float* out = (float*)d_out;

    const int block = 64;                 // 1 wave per block
    const int grid = BATCH / block;       // 1024 blocks, 4 blocks/CU
    net_kernel<<<grid, block, 0, stream>>>(x, w1, b1, w2, b2, fc1_w, fc1_b,
                                           fc2_w, fc2_b, out);
}